// Round 1
// baseline (1127.965 us; speedup 1.0000x reference)
//
#include <hip/hip_runtime.h>

typedef __attribute__((ext_vector_type(8))) short short8;
typedef __attribute__((ext_vector_type(4))) short short4v;
typedef __attribute__((ext_vector_type(4))) float float4v;
typedef __attribute__((ext_vector_type(2))) float float2v;

#define Hh 128
#define Ss 200
#define Ee 64
#define BR 16      // batch rows per block (GRU kernel)
#define TPB3 512   // 8 waves

// round-to-nearest-even float -> bf16 bits
__device__ __forceinline__ short f2bf(float f) {
    unsigned u = __float_as_uint(f);
    u += 0x7FFFu + ((u >> 16) & 1u);
    return (short)(u >> 16);
}

// ---------------- Kernel 1: bilinear attention + softmax -> att[B,S] ----------------
__global__ __launch_bounds__(256) void attn_kernel(
    const float* __restrict__ x, const float* __restrict__ tgt,
    const float* __restrict__ Wb, float* __restrict__ att)
{
    __shared__ float Wls[128][65];   // +1 pad -> conflict-free column dots
    __shared__ float tg[64];
    __shared__ float v[128];
    __shared__ float lg[Ss];
    __shared__ float redM, redZ;

    int tid = threadIdx.x;
    int b = blockIdx.x;

    if (tid < 64) tg[tid] = tgt[b * Ee + tid];
    for (int i = tid; i < 128 * 64; i += 256) Wls[i >> 6][i & 63] = Wb[i];
    __syncthreads();

    if (tid < 128) {
        float s = 0.f;
        #pragma unroll
        for (int e = 0; e < 64; ++e) s += Wls[tid][e] * tg[e];
        v[tid] = s;
    }
    __syncthreads();

    int wave = tid >> 6, lane = tid & 63;
    const float* xb = x + (size_t)b * Ss * Hh;
    for (int s = wave; s < Ss; s += 4) {
        float2v xv = *(const float2v*)&xb[s * Hh + lane * 2];
        float p = xv.x * v[2 * lane] + xv.y * v[2 * lane + 1];
        #pragma unroll
        for (int off = 32; off > 0; off >>= 1) p += __shfl_down(p, off);
        if (lane == 0) lg[s] = p;
    }
    __syncthreads();

    if (wave == 0) {
        float m = -1e30f;
        for (int s = lane; s < Ss; s += 64) m = fmaxf(m, lg[s]);
        #pragma unroll
        for (int off = 32; off > 0; off >>= 1) m = fmaxf(m, __shfl_down(m, off));
        m = __shfl(m, 0);
        float z = 0.f;
        for (int s = lane; s < Ss; s += 64) z += expf(lg[s] - m);
        #pragma unroll
        for (int off = 32; off > 0; off >>= 1) z += __shfl_down(z, off);
        if (lane == 0) { redM = m; redZ = 1.f / z; }
    }
    __syncthreads();

    float M = redM, Zi = redZ;
    for (int s = tid; s < Ss; s += 256)
        att[(size_t)b * Ss + s] = expf(lg[s] - M) * Zi;
}

// ---------------- Kernel 2: attention-gated GRU scan, weights register-resident ----------------
__global__ __launch_bounds__(TPB3, 2) void gru_kernel(
    const float* __restrict__ x, const float* __restrict__ att,
    const float* __restrict__ Wxu, const float* __restrict__ Whu, const float* __restrict__ bu,
    const float* __restrict__ Wxr, const float* __restrict__ Whr, const float* __restrict__ br,
    const float* __restrict__ Wxc, const float* __restrict__ Whc, const float* __restrict__ bc,
    float* __restrict__ out)
{
    // LDS: ~50.6 KB total
    __shared__ __align__(16) short xh[BR][264];   // [x(128) | h(128)] bf16, +8 pad (2-way banks, free)
    __shared__ __align__(16) short rhs[BR][136];  // r*h bf16, +8 pad
    __shared__ __align__(16) float G1[BR][260];   // u(cols 0..127), r(cols 128..255) fp32
    __shared__ __align__(16) float C2[BR][132];   // candidate c fp32
    __shared__ float attS[BR][Ss];                // this block's attention rows

    int tid = threadIdx.x;
    int wave = tid >> 6, lane = tid & 63;
    int quad = lane >> 4, l16 = lane & 15;
    int b0 = blockIdx.x * BR;

    // ---- one-time: weights -> bf16 MFMA B-fragments in registers ----
    // phase1: waves 0-3 own u cols (w*32..+31), waves 4-7 own r cols; K=256 = [x|h]
    // phase2: wave w owns c cols w*16..+15; K=256 = [x|r*h]
    short8 W1[2][8];
    short8 W2[8];
    #pragma unroll
    for (int t = 0; t < 2; ++t) {
        int fullcol = wave * 32 + t * 16 + l16;           // 0..255
        const float* Wx = (fullcol < 128) ? Wxu : Wxr;
        const float* Wh = (fullcol < 128) ? Whu : Whr;
        int n = fullcol & 127;
        #pragma unroll
        for (int q = 0; q < 8; ++q) {
            short8 f;
            #pragma unroll
            for (int j = 0; j < 8; ++j) {
                int k = q * 32 + quad * 8 + j;            // 0..255
                float wv = (k < 128) ? Wx[k * Hh + n] : Wh[(k - 128) * Hh + n];
                f[j] = f2bf(wv);
            }
            W1[t][q] = f;
        }
    }
    {
        int n2 = wave * 16 + l16;
        #pragma unroll
        for (int q = 0; q < 8; ++q) {
            short8 f;
            #pragma unroll
            for (int j = 0; j < 8; ++j) {
                int k = q * 32 + quad * 8 + j;
                float wv = (k < 128) ? Wxc[k * Hh + n2] : Whc[(k - 128) * Hh + n2];
                f[j] = f2bf(wv);
            }
            W2[q] = f;
        }
    }
    float b1[2];
    #pragma unroll
    for (int t = 0; t < 2; ++t) {
        int fullcol = wave * 32 + t * 16 + l16;
        b1[t] = (fullcol < 128) ? bu[fullcol] : br[fullcol - 128];
    }
    float b2 = bc[wave * 16 + l16];

    // ---- preload this block's attention weights ----
    for (int i = tid; i < BR * Ss; i += TPB3) {
        int rr = i / Ss, sc = i % Ss;
        attS[rr][sc] = att[(size_t)(b0 + rr) * Ss + sc];
    }

    // ---- updater mapping: thread owns (urow, 4 consecutive h columns) ----
    int urow = tid >> 5;            // 0..15
    int uc = (tid & 31) * 4;        // 0,4,...,124
    float hreg[4] = {0.f, 0.f, 0.f, 0.f};
    { short4v z = {0, 0, 0, 0}; *(short4v*)&xh[urow][128 + uc] = z; }   // h0 = 0

    const float* xrow = x + (size_t)(b0 + urow) * Ss * Hh + uc;
    float4v xv = *(const float4v*)&xrow[0];   // prefetch t=0

    for (int t = 0; t < Ss; ++t) {
        // stage x_t -> xh (bf16)
        {
            short4v xs;
            #pragma unroll
            for (int i = 0; i < 4; ++i) xs[i] = f2bf(xv[i]);
            *(short4v*)&xh[urow][uc] = xs;
        }
        __syncthreads();   // A: x + h staged

        // phase 1: pre_u / pre_r = [x|h] @ [Wx*;Wh*], then sigmoid -> G1
        float4v a0 = {0.f, 0.f, 0.f, 0.f}, a1 = {0.f, 0.f, 0.f, 0.f};
        #pragma unroll
        for (int q = 0; q < 8; ++q) {
            short8 af = *(const short8*)&xh[l16][q * 32 + quad * 8];
            a0 = __builtin_amdgcn_mfma_f32_16x16x32_bf16(af, W1[0][q], a0, 0, 0, 0);
            a1 = __builtin_amdgcn_mfma_f32_16x16x32_bf16(af, W1[1][q], a1, 0, 0, 0);
        }
        {
            int c0 = wave * 32 + l16;
            #pragma unroll
            for (int r = 0; r < 4; ++r) {
                int rr = quad * 4 + r;
                G1[rr][c0]      = 1.f / (1.f + expf(-(a0[r] + b1[0])));
                G1[rr][c0 + 16] = 1.f / (1.f + expf(-(a1[r] + b1[1])));
            }
        }
        __syncthreads();   // B: gates ready

        // r*h -> rhs (bf16)
        {
            short4v rv;
            #pragma unroll
            for (int i = 0; i < 4; ++i) rv[i] = f2bf(G1[urow][128 + uc + i] * hreg[i]);
            *(short4v*)&rhs[urow][uc] = rv;
        }
        __syncthreads();   // C: r*h staged

        // phase 2: pre_c = [x | r*h] @ [Wxc;Whc], tanh -> C2
        float4v a2 = {0.f, 0.f, 0.f, 0.f};
        #pragma unroll
        for (int q = 0; q < 4; ++q) {
            short8 af = *(const short8*)&xh[l16][q * 32 + quad * 8];
            a2 = __builtin_amdgcn_mfma_f32_16x16x32_bf16(af, W2[q], a2, 0, 0, 0);
        }
        #pragma unroll
        for (int q = 0; q < 4; ++q) {
            short8 af = *(const short8*)&rhs[l16][q * 32 + quad * 8];
            a2 = __builtin_amdgcn_mfma_f32_16x16x32_bf16(af, W2[q + 4], a2, 0, 0, 0);
        }
        {
            int c0 = wave * 16 + l16;
            #pragma unroll
            for (int r = 0; r < 4; ++r)
                C2[quad * 4 + r][c0] = tanhf(a2[r] + b2);
        }
        __syncthreads();   // D: candidate ready

        // prefetch next x (hidden behind update + barrier A)
        if (t + 1 < Ss) xv = *(const float4v*)&xrow[(size_t)(t + 1) * Hh];

        // h update (fp32 master copy in registers), restage h as bf16
        {
            float a = attS[urow][t];
            short4v hv;
            #pragma unroll
            for (int i = 0; i < 4; ++i) {
                float u = G1[urow][uc + i];
                float c = C2[urow][uc + i];
                float au = a * u;
                hreg[i] = (1.f - au) * hreg[i] + au * c;
                hv[i] = f2bf(hreg[i]);
            }
            *(short4v*)&xh[urow][128 + uc] = hv;
        }
    }

    // final h -> out[B,H]
    float4v o;
    #pragma unroll
    for (int i = 0; i < 4; ++i) o[i] = hreg[i];
    *(float4v*)&out[(size_t)(b0 + urow) * Hh + uc] = o;
}

extern "C" void kernel_launch(void* const* d_in, const int* in_sizes, int n_in,
                              void* d_out, int out_size, void* d_ws, size_t ws_size,
                              hipStream_t stream) {
    const float* x   = (const float*)d_in[0];   // [B,S,H]
    const float* tgt = (const float*)d_in[1];   // [B,E]
    const float* Wb  = (const float*)d_in[2];   // [H,E]
    const float* Wxu = (const float*)d_in[3];
    const float* Whu = (const float*)d_in[4];
    const float* bu  = (const float*)d_in[5];
    const float* Wxr = (const float*)d_in[6];
    const float* Whr = (const float*)d_in[7];
    const float* br  = (const float*)d_in[8];
    const float* Wxc = (const float*)d_in[9];
    const float* Whc = (const float*)d_in[10];
    const float* bc  = (const float*)d_in[11];
    float* out = (float*)d_out;

    const int B = in_sizes[1] / Ee;             // 4096
    float* att = (float*)d_ws;                  // [B,S] fp32, 3.3 MB

    attn_kernel<<<B, 256, 0, stream>>>(x, tgt, Wb, att);
    gru_kernel<<<B / BR, TPB3, 0, stream>>>(x, att, Wxu, Whu, bu,
                                            Wxr, Whr, br, Wxc, Whc, bc, out);
}

// Round 2
// 844.620 us; speedup vs baseline: 1.3355x; 1.3355x over previous
//
#include <hip/hip_runtime.h>

typedef __attribute__((ext_vector_type(8))) short short8;
typedef __attribute__((ext_vector_type(4))) short short4v;
typedef __attribute__((ext_vector_type(4))) float float4v;

#define Hh 128
#define Ss 200
#define Ee 64
#define BR 16      // batch rows per block (GRU kernel)
#define TPB3 512   // 8 waves

#if defined(__has_builtin) && __has_builtin(__builtin_amdgcn_exp2f)
#define EXP2F(x) __builtin_amdgcn_exp2f(x)
#else
#define EXP2F(x) exp2f(x)
#endif
#if defined(__has_builtin) && __has_builtin(__builtin_amdgcn_rcpf)
#define RCPF(x) __builtin_amdgcn_rcpf(x)
#else
#define RCPF(x) (1.0f / (x))
#endif

#define LOG2E 1.442695040888963f

__device__ __forceinline__ float fsig(float z) {
    return RCPF(1.0f + EXP2F(-LOG2E * z));       // 1/(1+e^-z), native exp/rcp
}
__device__ __forceinline__ float ftanh(float z) {
    return 1.0f - 2.0f * RCPF(1.0f + EXP2F(2.0f * LOG2E * z)); // saturates correctly at +-inf
}

// round-to-nearest-even float -> bf16 bits
__device__ __forceinline__ short f2bf(float f) {
    unsigned u = __float_as_uint(f);
    u += 0x7FFFu + ((u >> 16) & 1u);
    return (short)(u >> 16);
}
__device__ __forceinline__ float bf2f(short s) {
    return __uint_as_float(((unsigned)(unsigned short)s) << 16);
}

// ---------------- Kernel 0: v[b,:] = W_bil @ target[b,:]  (tiny) ----------------
__global__ __launch_bounds__(256) void v_kernel(
    const float* __restrict__ tgt, const float* __restrict__ Wb, float* __restrict__ v)
{
    __shared__ float tg[8][64];
    int tid = threadIdx.x;
    int b0 = blockIdx.x * 8;
    for (int i = tid; i < 8 * 64; i += 256) tg[i >> 6][i & 63] = tgt[(size_t)b0 * Ee + i];
    __syncthreads();

    int h = tid & 127, half = tid >> 7;
    float acc[4] = {0.f, 0.f, 0.f, 0.f};
    #pragma unroll
    for (int e4 = 0; e4 < 16; ++e4) {
        float4v wv = *(const float4v*)&Wb[h * Ee + e4 * 4];
        #pragma unroll
        for (int o = 0; o < 4; ++o) {
            float4v tv = *(const float4v*)&tg[half * 4 + o][e4 * 4];
            acc[o] += wv.x * tv.x + wv.y * tv.y + wv.z * tv.z + wv.w * tv.w;
        }
    }
    #pragma unroll
    for (int o = 0; o < 4; ++o)
        v[(size_t)(b0 + half * 4 + o) * Hh + h] = acc[o];
}

// ---------------- Kernel 1: logits + softmax -> att[B,S], thread-per-s ----------------
__global__ __launch_bounds__(256) void attn_kernel(
    const float* __restrict__ x, const float* __restrict__ v, float* __restrict__ att)
{
    __shared__ float vS[128];
    __shared__ float lg[256];
    __shared__ float redM, redZ;

    int tid = threadIdx.x;
    int b = blockIdx.x;

    if (tid < 128) vS[tid] = v[(size_t)b * Hh + tid];
    __syncthreads();

    float dot = 0.f;
    if (tid < Ss) {
        const float* xr = x + ((size_t)b * Ss + tid) * Hh;
        #pragma unroll 8
        for (int e4 = 0; e4 < 32; ++e4) {
            float4v xv = *(const float4v*)&xr[e4 * 4];
            dot += xv.x * vS[e4 * 4] + xv.y * vS[e4 * 4 + 1]
                 + xv.z * vS[e4 * 4 + 2] + xv.w * vS[e4 * 4 + 3];
        }
        lg[tid] = dot;
    }
    __syncthreads();

    if (tid < 64) {
        float m = -1e30f;
        for (int s = tid; s < Ss; s += 64) m = fmaxf(m, lg[s]);
        #pragma unroll
        for (int off = 32; off > 0; off >>= 1) m = fmaxf(m, __shfl_xor(m, off));
        float z = 0.f;
        for (int s = tid; s < Ss; s += 64) z += EXP2F((lg[s] - m) * LOG2E);
        #pragma unroll
        for (int off = 32; off > 0; off >>= 1) z += __shfl_xor(z, off);
        if (tid == 0) { redM = m; redZ = RCPF(z); }
    }
    __syncthreads();

    if (tid < Ss)
        att[(size_t)b * Ss + tid] = EXP2F((dot - redM) * LOG2E) * redZ;
}

// ---------------- Kernel 2: attention-gated GRU scan, weights register-resident ----------------
__global__ __launch_bounds__(TPB3) void gru_kernel(
    const float* __restrict__ x, const float* __restrict__ att,
    const float* __restrict__ Wxu, const float* __restrict__ Whu, const float* __restrict__ bu,
    const float* __restrict__ Wxr, const float* __restrict__ Whr, const float* __restrict__ br,
    const float* __restrict__ Wxc, const float* __restrict__ Whc, const float* __restrict__ bc,
    float* __restrict__ out)
{
    __shared__ __align__(16) short xh[BR][264];   // [x(128) | h(128)] bf16 (+8 pad)
    __shared__ __align__(16) short rhs[BR][136];  // r*h bf16 (+8 pad)
    __shared__ __align__(16) float G1[BR][132];   // u gate fp32 (+4 pad)
    __shared__ __align__(16) float C2[BR][132];   // candidate fp32 (+4 pad)
    __shared__ float attS[BR][Ss];

    int tid = threadIdx.x;
    int wave = tid >> 6, lane = tid & 63;
    int quad = lane >> 4, l16 = lane & 15;
    int b0 = blockIdx.x * BR;

    // ---- one-time: weights -> bf16 MFMA B-fragments in registers ----
    // phase1: waves 0-3 own u cols, waves 4-7 own r cols; K=256 = [x|h]
    // phase2: wave w owns c cols w*16..+15; K=256 = [x|r*h]
    short8 W1[2][8];
    short8 W2[8];
    #pragma unroll
    for (int t = 0; t < 2; ++t) {
        int fullcol = wave * 32 + t * 16 + l16;           // 0..255
        const float* Wx = (fullcol < 128) ? Wxu : Wxr;
        const float* Wh = (fullcol < 128) ? Whu : Whr;
        int n = fullcol & 127;
        #pragma unroll
        for (int q = 0; q < 8; ++q) {
            short8 f;
            #pragma unroll
            for (int j = 0; j < 8; ++j) {
                int k = q * 32 + quad * 8 + j;            // 0..255
                float wv = (k < 128) ? Wx[k * Hh + n] : Wh[(k - 128) * Hh + n];
                f[j] = f2bf(wv);
            }
            W1[t][q] = f;
        }
    }
    {
        int n2 = wave * 16 + l16;
        #pragma unroll
        for (int q = 0; q < 8; ++q) {
            short8 f;
            #pragma unroll
            for (int j = 0; j < 8; ++j) {
                int k = q * 32 + quad * 8 + j;
                float wv = (k < 128) ? Wxc[k * Hh + n2] : Whc[(k - 128) * Hh + n2];
                f[j] = f2bf(wv);
            }
            W2[q] = f;
        }
    }
    float b1[2];
    #pragma unroll
    for (int t = 0; t < 2; ++t) {
        int fullcol = wave * 32 + t * 16 + l16;
        b1[t] = (fullcol < 128) ? bu[fullcol] : br[fullcol - 128];
    }
    float b2 = bc[wave * 16 + l16];

    // ---- preload this block's attention weights ----
    for (int i = tid; i < BR * Ss; i += TPB3) {
        int rr = i / Ss, sc = i % Ss;
        attS[rr][sc] = att[(size_t)(b0 + rr) * Ss + sc];
    }

    // ---- updater mapping: thread owns (urow, 4 consecutive h columns) ----
    int urow = tid >> 5;            // 0..15
    int uc = (tid & 31) * 4;        // 0,4,...,124
    float hreg[4] = {0.f, 0.f, 0.f, 0.f};
    { short4v z = {0, 0, 0, 0}; *(short4v*)&xh[urow][128 + uc] = z; }   // h0 = 0

    const float* xrow = x + (size_t)(b0 + urow) * Ss * Hh + uc;
    float4v xv = *(const float4v*)&xrow[0];   // t=0
    float4v xvn = xv;

    #pragma unroll 1
    for (int t = 0; t < Ss; ++t) {
        // stage x_t -> xh (bf16)
        {
            short4v xs;
            #pragma unroll
            for (int i = 0; i < 4; ++i) xs[i] = f2bf(xv[i]);
            *(short4v*)&xh[urow][uc] = xs;
        }
        // prefetch x_{t+1} NOW: hiding window = the whole step
        if (t + 1 < Ss) xvn = *(const float4v*)&xrow[(size_t)(t + 1) * Hh];
        __syncthreads();   // A: x + h staged

        // phase 1: pre_u / pre_r = [x|h] @ [Wx*;Wh*]
        float4v a0 = {0.f, 0.f, 0.f, 0.f}, a1 = {0.f, 0.f, 0.f, 0.f};
        #pragma unroll
        for (int q = 0; q < 8; ++q) {
            short8 af = *(const short8*)&xh[l16][q * 32 + quad * 8];
            a0 = __builtin_amdgcn_mfma_f32_16x16x32_bf16(af, W1[0][q], a0, 0, 0, 0);
            a1 = __builtin_amdgcn_mfma_f32_16x16x32_bf16(af, W1[1][q], a1, 0, 0, 0);
        }
        if (wave < 4) {
            // u gates -> G1
            int c0 = wave * 32 + l16;
            #pragma unroll
            for (int r = 0; r < 4; ++r) {
                int rr = quad * 4 + r;
                G1[rr][c0]      = fsig(a0[r] + b1[0]);
                G1[rr][c0 + 16] = fsig(a1[r] + b1[1]);
            }
        } else {
            // r gates: compute r*h directly (h as bf16 from xh) -> rhs
            int c0 = (wave - 4) * 32 + l16;
            #pragma unroll
            for (int r = 0; r < 4; ++r) {
                int rr = quad * 4 + r;
                float r0 = fsig(a0[r] + b1[0]);
                float r1 = fsig(a1[r] + b1[1]);
                float h0 = bf2f(xh[rr][128 + c0]);
                float h1 = bf2f(xh[rr][128 + c0 + 16]);
                rhs[rr][c0]      = f2bf(r0 * h0);
                rhs[rr][c0 + 16] = f2bf(r1 * h1);
            }
        }
        __syncthreads();   // B: gates + r*h ready

        // phase 2: pre_c = [x | r*h] @ [Wxc;Whc], tanh -> C2
        float4v a2 = {0.f, 0.f, 0.f, 0.f};
        #pragma unroll
        for (int q = 0; q < 4; ++q) {
            short8 af = *(const short8*)&xh[l16][q * 32 + quad * 8];
            a2 = __builtin_amdgcn_mfma_f32_16x16x32_bf16(af, W2[q], a2, 0, 0, 0);
        }
        #pragma unroll
        for (int q = 0; q < 4; ++q) {
            short8 af = *(const short8*)&rhs[l16][q * 32 + quad * 8];
            a2 = __builtin_amdgcn_mfma_f32_16x16x32_bf16(af, W2[q + 4], a2, 0, 0, 0);
        }
        {
            int c0 = wave * 16 + l16;
            #pragma unroll
            for (int r = 0; r < 4; ++r)
                C2[quad * 4 + r][c0] = ftanh(a2[r] + b2);
        }
        __syncthreads();   // C: candidate ready

        // h update (fp32 master in registers), restage h as bf16
        {
            float a = attS[urow][t];
            short4v hv;
            #pragma unroll
            for (int i = 0; i < 4; ++i) {
                float u = G1[urow][uc + i];
                float c = C2[urow][uc + i];
                float au = a * u;
                hreg[i] = (1.f - au) * hreg[i] + au * c;
                hv[i] = f2bf(hreg[i]);
            }
            *(short4v*)&xh[urow][128 + uc] = hv;
        }
        xv = xvn;
    }

    // final h -> out[B,H]
    float4v o;
    #pragma unroll
    for (int i = 0; i < 4; ++i) o[i] = hreg[i];
    *(float4v*)&out[(size_t)(b0 + urow) * Hh + uc] = o;
}

extern "C" void kernel_launch(void* const* d_in, const int* in_sizes, int n_in,
                              void* d_out, int out_size, void* d_ws, size_t ws_size,
                              hipStream_t stream) {
    const float* x   = (const float*)d_in[0];   // [B,S,H]
    const float* tgt = (const float*)d_in[1];   // [B,E]
    const float* Wb  = (const float*)d_in[2];   // [H,E]
    const float* Wxu = (const float*)d_in[3];
    const float* Whu = (const float*)d_in[4];
    const float* bu  = (const float*)d_in[5];
    const float* Wxr = (const float*)d_in[6];
    const float* Whr = (const float*)d_in[7];
    const float* br  = (const float*)d_in[8];
    const float* Wxc = (const float*)d_in[9];
    const float* Whc = (const float*)d_in[10];
    const float* bc  = (const float*)d_in[11];
    float* out = (float*)d_out;

    const int B = in_sizes[1] / Ee;             // 4096
    float* att = (float*)d_ws;                  // [B,S] fp32
    float* v   = att + (size_t)B * Ss;          // [B,H] fp32

    v_kernel<<<B / 8, 256, 0, stream>>>(tgt, Wb, v);
    attn_kernel<<<B, 256, 0, stream>>>(x, v, att);
    gru_kernel<<<B / BR, TPB3, 0, stream>>>(x, att, Wxu, Whu, bu,
                                            Wxr, Whr, br, Wxc, Whc, bc, out);
}